// Round 15
// baseline (705.746 us; speedup 1.0000x reference)
//
#include <hip/hip_runtime.h>
#include <math.h>

// ---------------------------------------------------------------------------
// HGT transformer layer. N=50000, D=128, H=8, DH=16, E=300000 per edge type.
// R5:  CSR + fused online-softmax aggregation (5000 -> 872 us).
// R10: bf16x3 MFMA GEMMs (872 -> 744).
// R12: pre-split bf16 operands + 4-wide pipelined fused_agg (744 -> 677).
// R13: hierarchical scan (677 -> 579).
// R14: GEMM full-K-chunk staging: stage K=128 slab of A,B (hi/lo) in 136 KB
//      LDS, ONE barrier per chunk (was 8), 192 MFMAs back-to-back. GEMMs
//      were latency-exposed (2 barriers/BK=32, ~410 us total vs 110 floor).
// ---------------------------------------------------------------------------

using bf16x8 = __attribute__((ext_vector_type(8))) short;
using us8    = __attribute__((ext_vector_type(8))) unsigned short;
using f32x4  = __attribute__((ext_vector_type(4))) float;

__device__ __forceinline__ float gelu_exact(float x) {
    return 0.5f * x * (1.0f + erff(x * 0.70710678118654752f));
}
__device__ __forceinline__ unsigned short f2bf(float x) {  // RNE float->bf16
    unsigned int u = __float_as_uint(x);
    u += 0x7fffu + ((u >> 16) & 1u);
    return (unsigned short)(u >> 16);
}
__device__ __forceinline__ float bf2f(unsigned short h) {
    return __uint_as_float(((unsigned int)h) << 16);
}

// --------------------------- LayerNorm (rows of 128) -----------------------
__global__ __launch_bounds__(256) void ln_kernel(
    const float* __restrict__ x, const float* __restrict__ g,
    const float* __restrict__ b, float* __restrict__ outf,
    unsigned short* __restrict__ outh, unsigned short* __restrict__ outl,
    int nrows)
{
    int row  = (int)((blockIdx.x * 256 + threadIdx.x) >> 6);
    int lane = threadIdx.x & 63;
    if (row >= nrows) return;
    float2 xv = *(const float2*)&x[(size_t)row * 128 + lane * 2];
    float s = xv.x + xv.y;
#pragma unroll
    for (int off = 32; off >= 1; off >>= 1) s += __shfl_xor(s, off, 64);
    float mu = s * (1.0f / 128.0f);
    float d0 = xv.x - mu, d1 = xv.y - mu;
    float v = d0 * d0 + d1 * d1;
#pragma unroll
    for (int off = 32; off >= 1; off >>= 1) v += __shfl_xor(v, off, 64);
    float rs = rsqrtf(v * (1.0f / 128.0f) + 1e-5f);
    float2 gv = *(const float2*)&g[lane * 2];
    float2 bv = *(const float2*)&b[lane * 2];
    float o0 = d0 * rs * gv.x + bv.x;
    float o1 = d1 * rs * gv.y + bv.y;
    size_t idx = (size_t)row * 128 + lane * 2;
    if (outf) *(float2*)&outf[idx] = make_float2(o0, o1);
    unsigned short h0 = f2bf(o0), h1 = f2bf(o1);
    *(ushort2*)&outh[idx] = make_ushort2(h0, h1);
    *(ushort2*)&outl[idx] = make_ushort2(f2bf(o0 - bf2f(h0)), f2bf(o1 - bf2f(h1)));
}

// ------------- weight transpose + bf16 hi/lo split (once per call) ---------
__global__ __launch_bounds__(256) void transpose_split_w(
    const float* __restrict__ W, unsigned short* __restrict__ Wh,
    unsigned short* __restrict__ Wl, int K, int N)
{
    __shared__ unsigned short th[32][33], tl[32][33];
    int kt = blockIdx.x * 32, nt = blockIdx.y * 32;
    int tx = threadIdx.x & 31, ty = threadIdx.x >> 5;
#pragma unroll
    for (int j = 0; j < 32; j += 8) {
        float v = W[(size_t)(kt + ty + j) * N + nt + tx];
        unsigned short h = f2bf(v);
        th[ty + j][tx] = h;
        tl[ty + j][tx] = f2bf(v - bf2f(h));
    }
    __syncthreads();
#pragma unroll
    for (int j = 0; j < 32; j += 8) {
        size_t o = (size_t)(nt + ty + j) * K + kt + tx;
        Wh[o] = th[tx][ty + j];
        Wl[o] = tl[tx][ty + j];
    }
}

// ---------------- bf16x3 MFMA GEMM, full-K-chunk staging -------------------
// C = A@B + bias. A: [M][K] bf16 hi/lo. B: [N][K] bf16 hi/lo (pre-transposed).
// Per 128-K chunk: stage A[128][128],B[128][128] hi/lo (136 KB LDS, stride
// 136 shorts = 272B: 16B-aligned b128 reads, 2-way banks), ONE barrier, then
// 4 k-groups x 48 MFMA. acc += Ah*Bh + Ah*Bl + Al*Bh.
// EPI: 0:+bias 1:gelu 2:aux1+s*(acc+b)+(1-s)*aux2 3:aux1+acc+bias.
// OBF=1: write bf16 hi/lo (Ch,Cl) instead of f32 C. N%128==0, K%128==0.
template <int EPI, int OBF>
__global__ __launch_bounds__(256) void gemm_bfp(
    const unsigned short* __restrict__ Ah, const unsigned short* __restrict__ Al,
    const unsigned short* __restrict__ Bh, const unsigned short* __restrict__ Bl,
    const float* __restrict__ bias, float* __restrict__ C,
    unsigned short* __restrict__ Ch, unsigned short* __restrict__ Cl,
    int M, int N, int K,
    const float* __restrict__ aux1, const float* __restrict__ aux2,
    const float* __restrict__ skipp)
{
    const int LDT = 136;  // shorts; 272B row stride
    __shared__ __align__(16) unsigned short sAh[128 * 136], sAl[128 * 136];
    __shared__ __align__(16) unsigned short sBh[128 * 136], sBl[128 * 136];
    const int t    = threadIdx.x;
    const int bm   = blockIdx.x * 128;
    const int bn   = blockIdx.y * 128;
    const int lane = t & 63;
    const int wave = t >> 6;
    const int wm   = (wave >> 1) * 64;
    const int wn   = (wave & 1) * 64;
    const int lrow = lane & 15;
    const int lkg  = lane >> 4;

    const int s_row = t >> 1;           // 0..127 (A-row / B-col)
    const int s_off = (t & 1) * 64;     // shorts offset within 128-k chunk

    f32x4 acc[4][4] = {};

    for (int c0 = 0; c0 < K; c0 += 128) {
        if (c0) __syncthreads();  // prior compute must finish before restage
        // ---- stage full 128-K slab: 8 x 16B per thread per array
        {
            size_t ga = (size_t)(bm + s_row) * K + c0 + s_off;
            size_t gb = (size_t)(bn + s_row) * K + c0 + s_off;
            int ld = s_row * LDT + s_off;
#pragma unroll
            for (int j = 0; j < 8; ++j) {
                *(us8*)&sAh[ld + j * 8] = *(const us8*)&Ah[ga + j * 8];
                *(us8*)&sAl[ld + j * 8] = *(const us8*)&Al[ga + j * 8];
                *(us8*)&sBh[ld + j * 8] = *(const us8*)&Bh[gb + j * 8];
                *(us8*)&sBl[ld + j * 8] = *(const us8*)&Bl[gb + j * 8];
            }
        }
        __syncthreads();

        // ---- 4 k-groups of 32; 48 MFMA each, no barriers between
#pragma unroll
        for (int kk = 0; kk < 4; ++kk) {
            const int ko = kk * 32 + lkg * 8;
            bf16x8 ah[4], al[4];
#pragma unroll
            for (int mi = 0; mi < 4; ++mi) {
                int r = wm + mi * 16 + lrow;
                ah[mi] = *(const bf16x8*)&sAh[r * LDT + ko];
                al[mi] = *(const bf16x8*)&sAl[r * LDT + ko];
            }
#pragma unroll
            for (int ni = 0; ni < 4; ++ni) {
                int c = wn + ni * 16 + lrow;
                bf16x8 bh = *(const bf16x8*)&sBh[c * LDT + ko];
                bf16x8 bl = *(const bf16x8*)&sBl[c * LDT + ko];
#pragma unroll
                for (int mi = 0; mi < 4; ++mi) {
                    acc[mi][ni] = __builtin_amdgcn_mfma_f32_16x16x32_bf16(ah[mi], bh, acc[mi][ni], 0, 0, 0);
                    acc[mi][ni] = __builtin_amdgcn_mfma_f32_16x16x32_bf16(ah[mi], bl, acc[mi][ni], 0, 0, 0);
                    acc[mi][ni] = __builtin_amdgcn_mfma_f32_16x16x32_bf16(al[mi], bh, acc[mi][ni], 0, 0, 0);
                }
            }
        }
    }

    // ---- epilogue. C/D layout: col = lane&15, row = (lane>>4)*4 + reg
    float sgk = 0.0f;
    if (EPI == 2) sgk = 1.0f / (1.0f + expf(-skipp[0]));
#pragma unroll
    for (int mi = 0; mi < 4; ++mi) {
#pragma unroll
        for (int r4 = 0; r4 < 4; ++r4) {
            int row = bm + wm + mi * 16 + lkg * 4 + r4;
            if (row >= M) continue;
#pragma unroll
            for (int ni = 0; ni < 4; ++ni) {
                int col = bn + wn + ni * 16 + lrow;
                size_t cidx = (size_t)row * N + col;
                float v = acc[mi][ni][r4] + bias[col];
                if (EPI == 1) v = gelu_exact(v);
                if (EPI == 2) v = aux1[cidx] + sgk * v + (1.0f - sgk) * aux2[cidx];
                if (EPI == 3) v = aux1[cidx] + v;
                if (OBF) {
                    unsigned short h = f2bf(v);
                    Ch[cidx] = h;
                    Cl[cidx] = f2bf(v - bf2f(h));
                } else {
                    C[cidx] = v;
                }
            }
        }
    }
}

// ------------------- per-node relation transforms --------------------------
__global__ __launch_bounds__(256) void rel_transform(
    const float* __restrict__ kqv,
    const float* __restrict__ a_f, const float* __restrict__ m_f,
    const float* __restrict__ a_g, const float* __restrict__ m_g,
    const float* __restrict__ p_f, const float* __restrict__ p_g,
    float2* __restrict__ kvF, float2* __restrict__ kvG, int nnodes)
{
    __shared__ float sAf[8 * 16 * 17], sMf[8 * 16 * 17];
    __shared__ float sAg[8 * 16 * 17], sMg[8 * 16 * 17];
    for (int i = threadIdx.x; i < 2048; i += 256) {
        int o = (i >> 4) * 17 + (i & 15);
        sAf[o] = a_f[i]; sMf[o] = m_f[i];
        sAg[o] = a_g[i]; sMg[o] = m_g[i];
    }
    __syncthreads();
    int t = threadIdx.x;
    int f = t & 15, h = (t >> 4) & 7, nl = t >> 7;
    int n = blockIdx.x * 2 + nl;
    if (n >= nnodes) return;
    const float* kp = &kqv[(size_t)n * 384 + h * 16];
    const float* vp = kp + 256;
    float kd[16], vd[16];
#pragma unroll
    for (int i4 = 0; i4 < 4; ++i4) {
        float4 k4 = *(const float4*)&kp[i4 * 4];
        float4 v4 = *(const float4*)&vp[i4 * 4];
        kd[i4 * 4 + 0] = k4.x; kd[i4 * 4 + 1] = k4.y;
        kd[i4 * 4 + 2] = k4.z; kd[i4 * 4 + 3] = k4.w;
        vd[i4 * 4 + 0] = v4.x; vd[i4 * 4 + 1] = v4.y;
        vd[i4 * 4 + 2] = v4.z; vd[i4 * 4 + 3] = v4.w;
    }
    float rkf = 0.f, rkg = 0.f, rvf = 0.f, rvg = 0.f;
#pragma unroll
    for (int d = 0; d < 16; ++d) {
        int idx = (h * 16 + d) * 17 + f;
        rkf += kd[d] * sAf[idx];
        rkg += kd[d] * sAg[idx];
        rvf += vd[d] * sMf[idx];
        rvg += vd[d] * sMg[idx];
    }
    float cf = p_f[h] * 0.25f;
    float cg = p_g[h] * 0.25f;
    size_t o = (size_t)n * 128 + h * 16 + f;
    kvF[o] = make_float2(rkf * cf, rvf);
    kvG[o] = make_float2(rkg * cg, rvg);
}

// -------------------- CSR build ---------------------------------------------
__global__ __launch_bounds__(256) void zero_deg(int* __restrict__ deg, int n) {
    int i = blockIdx.x * 256 + threadIdx.x;
    if (i < n) deg[i] = 0;
}

__global__ __launch_bounds__(256) void count_deg(
    const int* __restrict__ edge, int E, int* __restrict__ deg)
{
    int e = blockIdx.x * 256 + threadIdx.x;
    if (e >= E) return;
    atomicAdd(&deg[edge[E + e]], 1);
}

__global__ __launch_bounds__(256) void scan_phaseA(
    const int* __restrict__ deg, int* __restrict__ bsum, int n)
{
    __shared__ int sm[256];
    int i = blockIdx.x * 256 + threadIdx.x;
    sm[threadIdx.x] = (i < n) ? deg[i] : 0;
    __syncthreads();
    for (int off = 128; off >= 1; off >>= 1) {
        if (threadIdx.x < off) sm[threadIdx.x] += sm[threadIdx.x + off];
        __syncthreads();
    }
    if (threadIdx.x == 0) bsum[blockIdx.x] = sm[0];
}

__global__ __launch_bounds__(256) void scan_phaseB(
    const int* __restrict__ bsum, int* __restrict__ boff, int nb)
{
    __shared__ int sm[256];
    int v = (threadIdx.x < nb) ? bsum[threadIdx.x] : 0;
    sm[threadIdx.x] = v;
    __syncthreads();
    for (int off = 1; off < 256; off <<= 1) {
        int tv = (threadIdx.x >= off) ? sm[threadIdx.x - off] : 0;
        __syncthreads();
        sm[threadIdx.x] += tv;
        __syncthreads();
    }
    if (threadIdx.x < nb) boff[threadIdx.x] = sm[threadIdx.x] - v;  // exclusive
}

__global__ __launch_bounds__(256) void scan_phaseC(
    const int* __restrict__ deg, const int* __restrict__ boff,
    int* __restrict__ rowptr, int* __restrict__ cursor, int n)
{
    __shared__ int sm[256];
    int i = blockIdx.x * 256 + threadIdx.x;
    int v = (i < n) ? deg[i] : 0;
    sm[threadIdx.x] = v;
    __syncthreads();
    for (int off = 1; off < 256; off <<= 1) {
        int tv = (threadIdx.x >= off) ? sm[threadIdx.x - off] : 0;
        __syncthreads();
        sm[threadIdx.x] += tv;
        __syncthreads();
    }
    int incl = sm[threadIdx.x];
    int base = boff[blockIdx.x];
    if (i < n) {
        int e = base + incl - v;
        rowptr[i] = e;
        cursor[i] = e;
        if (i == n - 1) rowptr[n] = base + incl;
    }
}

__global__ __launch_bounds__(256) void fill_csr(
    const int* __restrict__ edge, int E, int addbase,
    int* __restrict__ cursor, unsigned int* __restrict__ col)
{
    int e = blockIdx.x * 256 + threadIdx.x;
    if (e >= E) return;
    int src = edge[e], dst = edge[E + e];
    int pos = atomicAdd(&cursor[dst], 1);
    col[pos] = (unsigned int)(src + addbase);
}

// -------------- fused gather + softmax + gelu (4-wide pipelined) -----------
__global__ __launch_bounds__(256) void fused_agg(
    const int* __restrict__ rowptr, const unsigned int* __restrict__ col,
    const float* __restrict__ kqv, const float2* __restrict__ kv2,
    unsigned short* __restrict__ outh, unsigned short* __restrict__ outl,
    int nnodes)
{
    int task = blockIdx.x * 16 + (threadIdx.x >> 4);
    int f    = threadIdx.x & 15;
    if (task >= nnodes * 8) return;
    int dst = task >> 3, h = task & 7;
    const int foff = h * 16 + f;
    float q = kqv[(size_t)dst * 384 + 128 + foff];
    int i = rowptr[dst], end = rowptr[dst + 1];
    float s = 0.f, o = 0.f;
    for (; i + 4 <= end; i += 4) {
        unsigned int c0 = col[i],     c1 = col[i + 1];
        unsigned int c2 = col[i + 2], c3 = col[i + 3];
        float2 kv0 = kv2[(size_t)c0 * 128 + foff];
        float2 kv1 = kv2[(size_t)c1 * 128 + foff];
        float2 kv2v = kv2[(size_t)c2 * 128 + foff];
        float2 kv3 = kv2[(size_t)c3 * 128 + foff];
        float p0 = q * kv0.x, p1 = q * kv1.x, p2 = q * kv2v.x, p3 = q * kv3.x;
#pragma unroll
        for (int off = 1; off < 16; off <<= 1) {
            p0 += __shfl_xor(p0, off, 16);
            p1 += __shfl_xor(p1, off, 16);
            p2 += __shfl_xor(p2, off, 16);
            p3 += __shfl_xor(p3, off, 16);
        }
        float e0 = __expf(p0), e1 = __expf(p1), e2 = __expf(p2), e3 = __expf(p3);
        s += e0; o = fmaf(e0, kv0.y, o);
        s += e1; o = fmaf(e1, kv1.y, o);
        s += e2; o = fmaf(e2, kv2v.y, o);
        s += e3; o = fmaf(e3, kv3.y, o);
    }
    for (; i < end; ++i) {
        unsigned int cv = col[i];
        float2 kv = kv2[(size_t)cv * 128 + foff];
        float part = q * kv.x;
#pragma unroll
        for (int off = 1; off < 16; off <<= 1) part += __shfl_xor(part, off, 16);
        float ev = __expf(part);
        s += ev;
        o = fmaf(ev, kv.y, o);
    }
    float r = o / (s + 1e-16f);
    float gr = gelu_exact(r);
    unsigned short hh = f2bf(gr);
    size_t oidx = (size_t)dst * 128 + foff;
    outh[oidx] = hh;
    outl[oidx] = f2bf(gr - bf2f(hh));
}

// ---------------------------------------------------------------------------
extern "C" void kernel_launch(void* const* d_in, const int* in_sizes, int n_in,
                              void* d_out, int out_size, void* d_ws, size_t ws_size,
                              hipStream_t stream)
{
    const float* x     = (const float*)d_in[0];
    const int*   ef    = (const int*)d_in[1];
    const int*   eg    = (const int*)d_in[2];
    const float* kqv_w = (const float*)d_in[3];
    const float* kqv_b = (const float*)d_in[4];
    const float* a_f   = (const float*)d_in[5];
    const float* m_f   = (const float*)d_in[6];
    const float* p_f   = (const float*)d_in[7];
    const float* a_g   = (const float*)d_in[8];
    const float* m_g   = (const float*)d_in[9];
    const float* p_g   = (const float*)d_in[10];
    const float* out_w = (const float*)d_in[11];
    const float* out_b = (const float*)d_in[12];
    const float* skip  = (const float*)d_in[13];
    const float* ln1_g = (const float*)d_in[14];
    const float* ln1_b = (const float*)d_in[15];
    const float* ln2_g = (const float*)d_in[16];
    const float* ln2_b = (const float*)d_in[17];
    const float* w1    = (const float*)d_in[18];
    const float* b1    = (const float*)d_in[19];
    const float* w2    = (const float*)d_in[20];
    const float* b2    = (const float*)d_in[21];
    float* out = (float*)d_out;

    const int D  = 128;
    const int Nn = in_sizes[0] / D;   // 50000
    const int E1 = in_sizes[1] / 2;   // 300000
    const int E2 = in_sizes[2] / 2;   // 300000
    const int nb = (Nn + 255) / 256;  // scan blocks (196 <= 256)

    // ---- workspace layout (as R13).
    float* ws = (float*)d_ws;
    size_t ND = (size_t)Nn * D;
    float* xn   = ws;
    float* kqvb = xn + ND;
    float2* kvF = (float2*)(kqvb + 3 * ND);
    float2* kvG = kvF + ND;
    unsigned short* h1h = (unsigned short*)kvF;        // [Nn*512]
    unsigned short* h1l = h1h + (size_t)Nn * 512;
    unsigned short* abase = (unsigned short*)(ws + 8 * ND);
    unsigned short* xnh = abase;                       // [ND]
    unsigned short* xnl = abase + ND;
    unsigned short* ggh = abase;                       // overlay (disjoint life)
    unsigned short* ggl = abase + ND;
    unsigned short* kwh = (unsigned short*)(ws + 9 * ND);  // [384*128]
    unsigned short* kwl = kwh + 384 * 128;
    unsigned short* owh = kwl + 384 * 128;                 // [128*128]
    unsigned short* owl = owh + 128 * 128;
    unsigned short* w1h = owl + 128 * 128;                 // [512*128]
    unsigned short* w1l = w1h + 512 * 128;
    unsigned short* w2h = w1l + 512 * 128;                 // [128*512]
    unsigned short* w2l = w2h + 128 * 512;
    int* ibase  = (int*)(w2l + 128 * 512);
    int* deg    = ibase;
    int* rowptr = deg + Nn;
    int* cursor = rowptr + Nn + 1;
    int* bsum   = cursor + Nn;
    int* boff   = bsum + nb;
    unsigned int* col = (unsigned int*)(boff + nb);
    float* x1 = out;   // x1 staged in d_out

    const int ln_grid = (Nn + 3) / 4;
    const int mg = (Nn + 127) / 128;

    // 0. weight transpose+split (once per call; order independent)
    transpose_split_w<<<dim3(4, 12), 256, 0, stream>>>(kqv_w, kwh, kwl, 128, 384);
    transpose_split_w<<<dim3(4, 4),  256, 0, stream>>>(out_w, owh, owl, 128, 128);
    transpose_split_w<<<dim3(4, 16), 256, 0, stream>>>(w1,    w1h, w1l, 128, 512);
    transpose_split_w<<<dim3(16, 4), 256, 0, stream>>>(w2,    w2h, w2l, 512, 128);
    // 1. xn = LN1(x): f32 + bf16 split
    ln_kernel<<<ln_grid, 256, 0, stream>>>(x, ln1_g, ln1_b, xn, xnh, xnl, Nn);
    // 2. kqv = xn @ kqv_w + kqv_b (f32 out)
    gemm_bfp<0, 0><<<dim3(mg, 3), 256, 0, stream>>>(
        xnh, xnl, kwh, kwl, kqv_b, kqvb, nullptr, nullptr,
        Nn, 384, 128, nullptr, nullptr, nullptr);
    // 3. per-node relation transforms
    rel_transform<<<(Nn + 1) / 2, 256, 0, stream>>>(
        kqvb, a_f, m_f, a_g, m_g, p_f, p_g, kvF, kvG, Nn);
    // 4. CSR build (hierarchical scan)
    zero_deg<<<nb, 256, 0, stream>>>(deg, Nn);
    count_deg<<<(E1 + 255) / 256, 256, 0, stream>>>(ef, E1, deg);
    count_deg<<<(E2 + 255) / 256, 256, 0, stream>>>(eg, E2, deg);
    scan_phaseA<<<nb, 256, 0, stream>>>(deg, bsum, Nn);
    scan_phaseB<<<1, 256, 0, stream>>>(bsum, boff, nb);
    scan_phaseC<<<nb, 256, 0, stream>>>(deg, boff, rowptr, cursor, Nn);
    fill_csr<<<(E1 + 255) / 256, 256, 0, stream>>>(ef, E1, 0, cursor, col);
    fill_csr<<<(E2 + 255) / 256, 256, 0, stream>>>(eg, E2, Nn, cursor, col);
    // 5. fused agg -> gelu(agg) as bf16 split (gagg overlays xn bf16)
    fused_agg<<<(Nn * 8) / 16, 256, 0, stream>>>(
        rowptr, col, kqvb, kvF, ggh, ggl, Nn);
    // 6. x1 = x + sig*(gagg @ out_w + out_b) + (1-sig)*xn  (into d_out)
    gemm_bfp<2, 0><<<dim3(mg, 1), 256, 0, stream>>>(
        ggh, ggl, owh, owl, out_b, x1, nullptr, nullptr,
        Nn, 128, 128, x, xn, skip);
    // 7. xn2 = LN2(x1): bf16 split only (reuses xn bf16 slots)
    ln_kernel<<<ln_grid, 256, 0, stream>>>(x1, ln2_g, ln2_b, nullptr, xnh, xnl, Nn);
    // 8. h1 = gelu(xn2 @ w1 + b1) -> bf16 split (overlays kvF/kvG)
    gemm_bfp<1, 1><<<dim3(mg, 4), 256, 0, stream>>>(
        xnh, xnl, w1h, w1l, b1, nullptr, h1h, h1l,
        Nn, 512, 128, nullptr, nullptr, nullptr);
    // 9. out = x1 + h1 @ w2 + b2
    gemm_bfp<3, 0><<<dim3(mg, 1), 256, 0, stream>>>(
        h1h, h1l, w2h, w2l, b2, out, nullptr, nullptr,
        Nn, 128, 512, x1, nullptr, nullptr);
}

// Round 16
// 560.203 us; speedup vs baseline: 1.2598x; 1.2598x over previous
//
#include <hip/hip_runtime.h>
#include <math.h>

// ---------------------------------------------------------------------------
// HGT transformer layer. N=50000, D=128, H=8, DH=16, E=300000 per edge type.
// R5:  CSR + fused online-softmax aggregation (5000 -> 872 us).
// R10: bf16x3 MFMA GEMMs (872 -> 744).
// R12: pre-split bf16 operands + pipelined fused_agg (744 -> 677).
// R13: hierarchical scan (677 -> 579).
// R14: full-K-chunk 136KB-LDS GEMM REGRESSED (706; occupancy 10%, 1 blk/CU).
// R16: revert to R13 GEMM structure (BK=32, 2 barriers) but stage via async
//      __builtin_amdgcn_global_load_lds width=16 (m93->m97 lever, +69%):
//      linear 32KB LDS + XOR-swizzled source/read (2-way conflicts = free).
// ---------------------------------------------------------------------------

using bf16x8 = __attribute__((ext_vector_type(8))) short;
using f32x4  = __attribute__((ext_vector_type(4))) float;

__device__ __forceinline__ float gelu_exact(float x) {
    return 0.5f * x * (1.0f + erff(x * 0.70710678118654752f));
}
__device__ __forceinline__ unsigned short f2bf(float x) {  // RNE float->bf16
    unsigned int u = __float_as_uint(x);
    u += 0x7fffu + ((u >> 16) & 1u);
    return (unsigned short)(u >> 16);
}
__device__ __forceinline__ float bf2f(unsigned short h) {
    return __uint_as_float(((unsigned int)h) << 16);
}
__device__ __forceinline__ void gload_lds16(const void* g, void* l) {
    // async 16B/lane global->LDS; LDS dest = wave-uniform base + lane*16
    __builtin_amdgcn_global_load_lds(
        (const __attribute__((address_space(1))) unsigned int*)g,
        (__attribute__((address_space(3))) unsigned int*)l, 16, 0, 0);
}

// --------------------------- LayerNorm (rows of 128) -----------------------
__global__ __launch_bounds__(256) void ln_kernel(
    const float* __restrict__ x, const float* __restrict__ g,
    const float* __restrict__ b, float* __restrict__ outf,
    unsigned short* __restrict__ outh, unsigned short* __restrict__ outl,
    int nrows)
{
    int row  = (int)((blockIdx.x * 256 + threadIdx.x) >> 6);
    int lane = threadIdx.x & 63;
    if (row >= nrows) return;
    float2 xv = *(const float2*)&x[(size_t)row * 128 + lane * 2];
    float s = xv.x + xv.y;
#pragma unroll
    for (int off = 32; off >= 1; off >>= 1) s += __shfl_xor(s, off, 64);
    float mu = s * (1.0f / 128.0f);
    float d0 = xv.x - mu, d1 = xv.y - mu;
    float v = d0 * d0 + d1 * d1;
#pragma unroll
    for (int off = 32; off >= 1; off >>= 1) v += __shfl_xor(v, off, 64);
    float rs = rsqrtf(v * (1.0f / 128.0f) + 1e-5f);
    float2 gv = *(const float2*)&g[lane * 2];
    float2 bv = *(const float2*)&b[lane * 2];
    float o0 = d0 * rs * gv.x + bv.x;
    float o1 = d1 * rs * gv.y + bv.y;
    size_t idx = (size_t)row * 128 + lane * 2;
    if (outf) *(float2*)&outf[idx] = make_float2(o0, o1);
    unsigned short h0 = f2bf(o0), h1 = f2bf(o1);
    *(ushort2*)&outh[idx] = make_ushort2(h0, h1);
    *(ushort2*)&outl[idx] = make_ushort2(f2bf(o0 - bf2f(h0)), f2bf(o1 - bf2f(h1)));
}

// ------------- weight transpose + bf16 hi/lo split (once per call) ---------
__global__ __launch_bounds__(256) void transpose_split_w(
    const float* __restrict__ W, unsigned short* __restrict__ Wh,
    unsigned short* __restrict__ Wl, int K, int N)
{
    __shared__ unsigned short th[32][33], tl[32][33];
    int kt = blockIdx.x * 32, nt = blockIdx.y * 32;
    int tx = threadIdx.x & 31, ty = threadIdx.x >> 5;
#pragma unroll
    for (int j = 0; j < 32; j += 8) {
        float v = W[(size_t)(kt + ty + j) * N + nt + tx];
        unsigned short h = f2bf(v);
        th[ty + j][tx] = h;
        tl[ty + j][tx] = f2bf(v - bf2f(h));
    }
    __syncthreads();
#pragma unroll
    for (int j = 0; j < 32; j += 8) {
        size_t o = (size_t)(nt + ty + j) * K + kt + tx;
        Wh[o] = th[tx][ty + j];
        Wl[o] = tl[tx][ty + j];
    }
}

// ---------------- bf16x3 MFMA GEMM, global_load_lds staging ----------------
// C = A@B + bias. A: [M][K] bf16 hi/lo. B: [N][K] bf16 hi/lo (pre-transposed).
// BK=32 single-buffered (m97 structure). LDS: linear [128][32] shorts per
// array (32KB total). Staging: 8x async global_load_lds(16B); source k-chunk
// pre-swizzled by slot = chunk ^ ((row>>1)&3); reads use the same XOR ->
// 2-way bank conflicts (free). acc += Ah*Bh + Ah*Bl + Al*Bh.
// EPI: 0:+bias 1:gelu 2:aux1+s*(acc+b)+(1-s)*aux2 3:aux1+acc+bias.
// OBF=1: write bf16 hi/lo (Ch,Cl). Requires N%128==0, K%32==0.
template <int EPI, int OBF>
__global__ __launch_bounds__(256) void gemm_bfp(
    const unsigned short* __restrict__ Ah, const unsigned short* __restrict__ Al,
    const unsigned short* __restrict__ Bh, const unsigned short* __restrict__ Bl,
    const float* __restrict__ bias, float* __restrict__ C,
    unsigned short* __restrict__ Ch, unsigned short* __restrict__ Cl,
    int M, int N, int K,
    const float* __restrict__ aux1, const float* __restrict__ aux2,
    const float* __restrict__ skipp)
{
    __shared__ __align__(16) unsigned short sAh[4096], sAl[4096];
    __shared__ __align__(16) unsigned short sBh[4096], sBl[4096];
    const int t    = threadIdx.x;
    const int bm   = blockIdx.x * 128;
    const int bn   = blockIdx.y * 128;
    const int lane = t & 63;
    const int wave = t >> 6;
    const int wm   = (wave >> 1) * 64;
    const int wn   = (wave & 1) * 64;
    const int lrow = lane & 15;
    const int lkg  = lane >> 4;

    // staging coords: lane l of wave w -> row j*64 + w*16 + (l>>2), slot l&3
    const int srow_b = (wave << 4) + (lane >> 2);
    const int slot   = lane & 3;
    const int lbase  = wave << 9;  // shorts; lane*8 added by HW

    f32x4 acc[4][4] = {};

    for (int k0 = 0; k0 < K; k0 += 32) {
        if (k0) __syncthreads();  // all waves done reading prev tile
#pragma unroll
        for (int j = 0; j < 2; ++j) {
            int row   = j * 64 + srow_b;
            int chunk = slot ^ ((row >> 1) & 3);   // pre-swizzled source
            size_t ga = (size_t)(bm + row) * K + k0 + chunk * 8;
            size_t gb = (size_t)(bn + row) * K + k0 + chunk * 8;
            int ld = j * 2048 + lbase;
            gload_lds16(&Ah[ga], &sAh[ld]);
            gload_lds16(&Al[ga], &sAl[ld]);
            gload_lds16(&Bh[gb], &sBh[ld]);
            gload_lds16(&Bl[gb], &sBl[ld]);
        }
        __syncthreads();  // drains vmcnt -> staged data visible

        bf16x8 ah[4], al[4];
#pragma unroll
        for (int mi = 0; mi < 4; ++mi) {
            int r = wm + mi * 16 + lrow;
            int off = r * 32 + (lkg ^ ((r >> 1) & 3)) * 8;  // swizzled read
            ah[mi] = *(const bf16x8*)&sAh[off];
            al[mi] = *(const bf16x8*)&sAl[off];
        }
#pragma unroll
        for (int ni = 0; ni < 4; ++ni) {
            int c = wn + ni * 16 + lrow;
            int off = c * 32 + (lkg ^ ((c >> 1) & 3)) * 8;
            bf16x8 bh = *(const bf16x8*)&sBh[off];
            bf16x8 bl = *(const bf16x8*)&sBl[off];
#pragma unroll
            for (int mi = 0; mi < 4; ++mi) {
                acc[mi][ni] = __builtin_amdgcn_mfma_f32_16x16x32_bf16(ah[mi], bh, acc[mi][ni], 0, 0, 0);
                acc[mi][ni] = __builtin_amdgcn_mfma_f32_16x16x32_bf16(ah[mi], bl, acc[mi][ni], 0, 0, 0);
                acc[mi][ni] = __builtin_amdgcn_mfma_f32_16x16x32_bf16(al[mi], bh, acc[mi][ni], 0, 0, 0);
            }
        }
    }

    // ---- epilogue. C/D layout: col = lane&15, row = (lane>>4)*4 + reg
    float sgk = 0.0f;
    if (EPI == 2) sgk = 1.0f / (1.0f + expf(-skipp[0]));
#pragma unroll
    for (int mi = 0; mi < 4; ++mi) {
#pragma unroll
        for (int r4 = 0; r4 < 4; ++r4) {
            int row = bm + wm + mi * 16 + lkg * 4 + r4;
            if (row >= M) continue;
#pragma unroll
            for (int ni = 0; ni < 4; ++ni) {
                int col = bn + wn + ni * 16 + lrow;
                size_t cidx = (size_t)row * N + col;
                float v = acc[mi][ni][r4] + bias[col];
                if (EPI == 1) v = gelu_exact(v);
                if (EPI == 2) v = aux1[cidx] + sgk * v + (1.0f - sgk) * aux2[cidx];
                if (EPI == 3) v = aux1[cidx] + v;
                if (OBF) {
                    unsigned short h = f2bf(v);
                    Ch[cidx] = h;
                    Cl[cidx] = f2bf(v - bf2f(h));
                } else {
                    C[cidx] = v;
                }
            }
        }
    }
}

// ------------------- per-node relation transforms --------------------------
__global__ __launch_bounds__(256) void rel_transform(
    const float* __restrict__ kqv,
    const float* __restrict__ a_f, const float* __restrict__ m_f,
    const float* __restrict__ a_g, const float* __restrict__ m_g,
    const float* __restrict__ p_f, const float* __restrict__ p_g,
    float2* __restrict__ kvF, float2* __restrict__ kvG, int nnodes)
{
    __shared__ float sAf[8 * 16 * 17], sMf[8 * 16 * 17];
    __shared__ float sAg[8 * 16 * 17], sMg[8 * 16 * 17];
    for (int i = threadIdx.x; i < 2048; i += 256) {
        int o = (i >> 4) * 17 + (i & 15);
        sAf[o] = a_f[i]; sMf[o] = m_f[i];
        sAg[o] = a_g[i]; sMg[o] = m_g[i];
    }
    __syncthreads();
    int t = threadIdx.x;
    int f = t & 15, h = (t >> 4) & 7, nl = t >> 7;
    int n = blockIdx.x * 2 + nl;
    if (n >= nnodes) return;
    const float* kp = &kqv[(size_t)n * 384 + h * 16];
    const float* vp = kp + 256;
    float kd[16], vd[16];
#pragma unroll
    for (int i4 = 0; i4 < 4; ++i4) {
        float4 k4 = *(const float4*)&kp[i4 * 4];
        float4 v4 = *(const float4*)&vp[i4 * 4];
        kd[i4 * 4 + 0] = k4.x; kd[i4 * 4 + 1] = k4.y;
        kd[i4 * 4 + 2] = k4.z; kd[i4 * 4 + 3] = k4.w;
        vd[i4 * 4 + 0] = v4.x; vd[i4 * 4 + 1] = v4.y;
        vd[i4 * 4 + 2] = v4.z; vd[i4 * 4 + 3] = v4.w;
    }
    float rkf = 0.f, rkg = 0.f, rvf = 0.f, rvg = 0.f;
#pragma unroll
    for (int d = 0; d < 16; ++d) {
        int idx = (h * 16 + d) * 17 + f;
        rkf += kd[d] * sAf[idx];
        rkg += kd[d] * sAg[idx];
        rvf += vd[d] * sMf[idx];
        rvg += vd[d] * sMg[idx];
    }
    float cf = p_f[h] * 0.25f;
    float cg = p_g[h] * 0.25f;
    size_t o = (size_t)n * 128 + h * 16 + f;
    kvF[o] = make_float2(rkf * cf, rvf);
    kvG[o] = make_float2(rkg * cg, rvg);
}

// -------------------- CSR build ---------------------------------------------
__global__ __launch_bounds__(256) void zero_deg(int* __restrict__ deg, int n) {
    int i = blockIdx.x * 256 + threadIdx.x;
    if (i < n) deg[i] = 0;
}

__global__ __launch_bounds__(256) void count_deg(
    const int* __restrict__ edge, int E, int* __restrict__ deg)
{
    int e = blockIdx.x * 256 + threadIdx.x;
    if (e >= E) return;
    atomicAdd(&deg[edge[E + e]], 1);
}

__global__ __launch_bounds__(256) void scan_phaseA(
    const int* __restrict__ deg, int* __restrict__ bsum, int n)
{
    __shared__ int sm[256];
    int i = blockIdx.x * 256 + threadIdx.x;
    sm[threadIdx.x] = (i < n) ? deg[i] : 0;
    __syncthreads();
    for (int off = 128; off >= 1; off >>= 1) {
        if (threadIdx.x < off) sm[threadIdx.x] += sm[threadIdx.x + off];
        __syncthreads();
    }
    if (threadIdx.x == 0) bsum[blockIdx.x] = sm[0];
}

__global__ __launch_bounds__(256) void scan_phaseB(
    const int* __restrict__ bsum, int* __restrict__ boff, int nb)
{
    __shared__ int sm[256];
    int v = (threadIdx.x < nb) ? bsum[threadIdx.x] : 0;
    sm[threadIdx.x] = v;
    __syncthreads();
    for (int off = 1; off < 256; off <<= 1) {
        int tv = (threadIdx.x >= off) ? sm[threadIdx.x - off] : 0;
        __syncthreads();
        sm[threadIdx.x] += tv;
        __syncthreads();
    }
    if (threadIdx.x < nb) boff[threadIdx.x] = sm[threadIdx.x] - v;  // exclusive
}

__global__ __launch_bounds__(256) void scan_phaseC(
    const int* __restrict__ deg, const int* __restrict__ boff,
    int* __restrict__ rowptr, int* __restrict__ cursor, int n)
{
    __shared__ int sm[256];
    int i = blockIdx.x * 256 + threadIdx.x;
    int v = (i < n) ? deg[i] : 0;
    sm[threadIdx.x] = v;
    __syncthreads();
    for (int off = 1; off < 256; off <<= 1) {
        int tv = (threadIdx.x >= off) ? sm[threadIdx.x - off] : 0;
        __syncthreads();
        sm[threadIdx.x] += tv;
        __syncthreads();
    }
    int incl = sm[threadIdx.x];
    int base = boff[blockIdx.x];
    if (i < n) {
        int e = base + incl - v;
        rowptr[i] = e;
        cursor[i] = e;
        if (i == n - 1) rowptr[n] = base + incl;
    }
}

__global__ __launch_bounds__(256) void fill_csr(
    const int* __restrict__ edge, int E, int addbase,
    int* __restrict__ cursor, unsigned int* __restrict__ col)
{
    int e = blockIdx.x * 256 + threadIdx.x;
    if (e >= E) return;
    int src = edge[e], dst = edge[E + e];
    int pos = atomicAdd(&cursor[dst], 1);
    col[pos] = (unsigned int)(src + addbase);
}

// -------------- fused gather + softmax + gelu (4-wide pipelined) -----------
__global__ __launch_bounds__(256) void fused_agg(
    const int* __restrict__ rowptr, const unsigned int* __restrict__ col,
    const float* __restrict__ kqv, const float2* __restrict__ kv2,
    unsigned short* __restrict__ outh, unsigned short* __restrict__ outl,
    int nnodes)
{
    int task = blockIdx.x * 16 + (threadIdx.x >> 4);
    int f    = threadIdx.x & 15;
    if (task >= nnodes * 8) return;
    int dst = task >> 3, h = task & 7;
    const int foff = h * 16 + f;
    float q = kqv[(size_t)dst * 384 + 128 + foff];
    int i = rowptr[dst], end = rowptr[dst + 1];
    float s = 0.f, o = 0.f;
    for (; i + 4 <= end; i += 4) {
        unsigned int c0 = col[i],     c1 = col[i + 1];
        unsigned int c2 = col[i + 2], c3 = col[i + 3];
        float2 kv0 = kv2[(size_t)c0 * 128 + foff];
        float2 kv1 = kv2[(size_t)c1 * 128 + foff];
        float2 kv2v = kv2[(size_t)c2 * 128 + foff];
        float2 kv3 = kv2[(size_t)c3 * 128 + foff];
        float p0 = q * kv0.x, p1 = q * kv1.x, p2 = q * kv2v.x, p3 = q * kv3.x;
#pragma unroll
        for (int off = 1; off < 16; off <<= 1) {
            p0 += __shfl_xor(p0, off, 16);
            p1 += __shfl_xor(p1, off, 16);
            p2 += __shfl_xor(p2, off, 16);
            p3 += __shfl_xor(p3, off, 16);
        }
        float e0 = __expf(p0), e1 = __expf(p1), e2 = __expf(p2), e3 = __expf(p3);
        s += e0; o = fmaf(e0, kv0.y, o);
        s += e1; o = fmaf(e1, kv1.y, o);
        s += e2; o = fmaf(e2, kv2v.y, o);
        s += e3; o = fmaf(e3, kv3.y, o);
    }
    for (; i < end; ++i) {
        unsigned int cv = col[i];
        float2 kv = kv2[(size_t)cv * 128 + foff];
        float part = q * kv.x;
#pragma unroll
        for (int off = 1; off < 16; off <<= 1) part += __shfl_xor(part, off, 16);
        float ev = __expf(part);
        s += ev;
        o = fmaf(ev, kv.y, o);
    }
    float r = o / (s + 1e-16f);
    float gr = gelu_exact(r);
    unsigned short hh = f2bf(gr);
    size_t oidx = (size_t)dst * 128 + foff;
    outh[oidx] = hh;
    outl[oidx] = f2bf(gr - bf2f(hh));
}

// ---------------------------------------------------------------------------
extern "C" void kernel_launch(void* const* d_in, const int* in_sizes, int n_in,
                              void* d_out, int out_size, void* d_ws, size_t ws_size,
                              hipStream_t stream)
{
    const float* x     = (const float*)d_in[0];
    const int*   ef    = (const int*)d_in[1];
    const int*   eg    = (const int*)d_in[2];
    const float* kqv_w = (const float*)d_in[3];
    const float* kqv_b = (const float*)d_in[4];
    const float* a_f   = (const float*)d_in[5];
    const float* m_f   = (const float*)d_in[6];
    const float* p_f   = (const float*)d_in[7];
    const float* a_g   = (const float*)d_in[8];
    const float* m_g   = (const float*)d_in[9];
    const float* p_g   = (const float*)d_in[10];
    const float* out_w = (const float*)d_in[11];
    const float* out_b = (const float*)d_in[12];
    const float* skip  = (const float*)d_in[13];
    const float* ln1_g = (const float*)d_in[14];
    const float* ln1_b = (const float*)d_in[15];
    const float* ln2_g = (const float*)d_in[16];
    const float* ln2_b = (const float*)d_in[17];
    const float* w1    = (const float*)d_in[18];
    const float* b1    = (const float*)d_in[19];
    const float* w2    = (const float*)d_in[20];
    const float* b2    = (const float*)d_in[21];
    float* out = (float*)d_out;

    const int D  = 128;
    const int Nn = in_sizes[0] / D;   // 50000
    const int E1 = in_sizes[1] / 2;   // 300000
    const int E2 = in_sizes[2] / 2;   // 300000
    const int nb = (Nn + 255) / 256;  // scan blocks (196 <= 256)

    // ---- workspace layout (as R13).
    float* ws = (float*)d_ws;
    size_t ND = (size_t)Nn * D;
    float* xn   = ws;
    float* kqvb = xn + ND;
    float2* kvF = (float2*)(kqvb + 3 * ND);
    float2* kvG = kvF + ND;
    unsigned short* h1h = (unsigned short*)kvF;        // [Nn*512]
    unsigned short* h1l = h1h + (size_t)Nn * 512;
    unsigned short* abase = (unsigned short*)(ws + 8 * ND);
    unsigned short* xnh = abase;                       // [ND]
    unsigned short* xnl = abase + ND;
    unsigned short* ggh = abase;                       // overlay (disjoint life)
    unsigned short* ggl = abase + ND;
    unsigned short* kwh = (unsigned short*)(ws + 9 * ND);  // [384*128]
    unsigned short* kwl = kwh + 384 * 128;
    unsigned short* owh = kwl + 384 * 128;                 // [128*128]
    unsigned short* owl = owh + 128 * 128;
    unsigned short* w1h = owl + 128 * 128;                 // [512*128]
    unsigned short* w1l = w1h + 512 * 128;
    unsigned short* w2h = w1l + 512 * 128;                 // [128*512]
    unsigned short* w2l = w2h + 128 * 512;
    int* ibase  = (int*)(w2l + 128 * 512);
    int* deg    = ibase;
    int* rowptr = deg + Nn;
    int* cursor = rowptr + Nn + 1;
    int* bsum   = cursor + Nn;
    int* boff   = bsum + nb;
    unsigned int* col = (unsigned int*)(boff + nb);
    float* x1 = out;   // x1 staged in d_out

    const int ln_grid = (Nn + 3) / 4;
    const int mg = (Nn + 127) / 128;

    // 0. weight transpose+split (once per call; order independent)
    transpose_split_w<<<dim3(4, 12), 256, 0, stream>>>(kqv_w, kwh, kwl, 128, 384);
    transpose_split_w<<<dim3(4, 4),  256, 0, stream>>>(out_w, owh, owl, 128, 128);
    transpose_split_w<<<dim3(4, 16), 256, 0, stream>>>(w1,    w1h, w1l, 128, 512);
    transpose_split_w<<<dim3(16, 4), 256, 0, stream>>>(w2,    w2h, w2l, 512, 128);
    // 1. xn = LN1(x): f32 + bf16 split
    ln_kernel<<<ln_grid, 256, 0, stream>>>(x, ln1_g, ln1_b, xn, xnh, xnl, Nn);
    // 2. kqv = xn @ kqv_w + kqv_b (f32 out)
    gemm_bfp<0, 0><<<dim3(mg, 3), 256, 0, stream>>>(
        xnh, xnl, kwh, kwl, kqv_b, kqvb, nullptr, nullptr,
        Nn, 384, 128, nullptr, nullptr, nullptr);
    // 3. per-node relation transforms
    rel_transform<<<(Nn + 1) / 2, 256, 0, stream>>>(
        kqvb, a_f, m_f, a_g, m_g, p_f, p_g, kvF, kvG, Nn);
    // 4. CSR build (hierarchical scan)
    zero_deg<<<nb, 256, 0, stream>>>(deg, Nn);
    count_deg<<<(E1 + 255) / 256, 256, 0, stream>>>(ef, E1, deg);
    count_deg<<<(E2 + 255) / 256, 256, 0, stream>>>(eg, E2, deg);
    scan_phaseA<<<nb, 256, 0, stream>>>(deg, bsum, Nn);
    scan_phaseB<<<1, 256, 0, stream>>>(bsum, boff, nb);
    scan_phaseC<<<nb, 256, 0, stream>>>(deg, boff, rowptr, cursor, Nn);
    fill_csr<<<(E1 + 255) / 256, 256, 0, stream>>>(ef, E1, 0, cursor, col);
    fill_csr<<<(E2 + 255) / 256, 256, 0, stream>>>(eg, E2, Nn, cursor, col);
    // 5. fused agg -> gelu(agg) as bf16 split (gagg overlays xn bf16)
    fused_agg<<<(Nn * 8) / 16, 256, 0, stream>>>(
        rowptr, col, kqvb, kvF, ggh, ggl, Nn);
    // 6. x1 = x + sig*(gagg @ out_w + out_b) + (1-sig)*xn  (into d_out)
    gemm_bfp<2, 0><<<dim3(mg, 1), 256, 0, stream>>>(
        ggh, ggl, owh, owl, out_b, x1, nullptr, nullptr,
        Nn, 128, 128, x, xn, skip);
    // 7. xn2 = LN2(x1): bf16 split only (reuses xn bf16 slots)
    ln_kernel<<<ln_grid, 256, 0, stream>>>(x1, ln2_g, ln2_b, nullptr, xnh, xnl, Nn);
    // 8. h1 = gelu(xn2 @ w1 + b1) -> bf16 split (overlays kvF/kvG)
    gemm_bfp<1, 1><<<dim3(mg, 4), 256, 0, stream>>>(
        xnh, xnl, w1h, w1l, b1, nullptr, h1h, h1l,
        Nn, 512, 128, nullptr, nullptr, nullptr);
    // 9. out = x1 + h1 @ w2 + b2
    gemm_bfp<3, 0><<<dim3(mg, 1), 256, 0, stream>>>(
        h1h, h1l, w2h, w2l, b2, out, nullptr, nullptr,
        Nn, 128, 512, x1, nullptr, nullptr);
}